// Round 16
// baseline (164.298 us; speedup 1.0000x reference)
//
#include <hip/hip_runtime.h>

// LightGCN, z-form: z = dis(.)x  =>  z_k[c] = invdeg_c * sum_{r->c} z_{k-1}[r]
//   out = 0.25*(emb + sdeg (.) (z1+z2+z3)).
// Build: radix partition by target bucket (128 nodes); per-bucket counting
// sort -> pad8 per-node CSR (dummy src = n -> zero row). NO per-node source
// sort (R11 global=75us, R15 LDS=31us+3.2M bank conflicts; saves only ~6us).
// Prop: DIM-SLICED. z stored [4 slices][n+1][16 dims]; block bid handles
// slice bid&3 -> per-XCD gather working set 3.2MB < 4MB L2 (round-robin
// bid->XCD) so gathers are L2 hits; fill drops 97->~50MB/prop. 4 lanes/node
// (lane = 4 dims = uint2), 16 nodes/wave, 8-edge unroll, v_dot2 accumulate.
// NOTES: coop fusion (R8/R9) 6x slower. MLP/instr changes on the old full-
// row prop were null (R9/R10/R12) — it was L2-fill-fabric-bound at 97MB.

#define BKT_SHIFT 7
#define BKT_NODES 128
#define BKT_CAP   2816      // mean 1600 edges + pad8 + slack
#define EPB       4096      // edges per k_bin block (306 blocks, 16/thread)

__device__ __forceinline__ float lo2f(unsigned u) { return __uint_as_float(u << 16); }
__device__ __forceinline__ float hi2f(unsigned u) { return __uint_as_float(u & 0xFFFF0000u); }
__device__ __forceinline__ unsigned cvt_pk_bf16(float lo, float hi) {
  unsigned r;
  asm("v_cvt_pk_bf16_f32 %0, %1, %2" : "=v"(r) : "v"(lo), "v"(hi));
  return r;
}

// s_lo += bf16_lo(u); s_hi += bf16_hi(u)  — one v_dot2 each (B=(1,0)/(0,1))
#define ACC2(u, slo, shi)                                                     \
  asm("v_dot2_f32_bf16 %0, %1, %2, %0" : "+v"(slo) : "v"(u), "v"(c_lo));      \
  asm("v_dot2_f32_bf16 %0, %1, %2, %0" : "+v"(shi) : "v"(u), "v"(c_hi));

__device__ __forceinline__ int wave_scan_incl(int v, int lane) {
#pragma unroll
  for (int off = 1; off < 64; off <<= 1) {
    int t = __shfl_up(v, off, 64);
    if (lane >= off) v += t;
  }
  return v;
}

// init bucket cursors + zero the dummy row n of each slice of z0/z1/z2
__global__ void k_init(int* __restrict__ bcursor, int nbkt,
                       unsigned* __restrict__ z0, unsigned* __restrict__ z1,
                       unsigned* __restrict__ z2, int n, int sstu) {
  int i = blockIdx.x * blockDim.x + threadIdx.x;
  if (i < nbkt) bcursor[i] = i * BKT_CAP;
  if (blockIdx.x == 0 && threadIdx.x < 32) {   // 4 slices x 8 uints
    int s = threadIdx.x >> 3, u = threadIdx.x & 7;
    size_t o = (size_t)s * sstu + (size_t)n * 8 + u;
    z0[o] = 0u; z1[o] = 0u; z2[o] = 0u;
  }
}

// radix partition by target bucket; col read ONCE into registers (int4),
// 4-wide unrolled LDS-atomic phases, grouped reservation.
__global__ __launch_bounds__(256)
void k_bin(const int* __restrict__ row, const int* __restrict__ col,
           int* __restrict__ bcursor, int* __restrict__ tmp, int E, int nbkt) {
  __shared__ int h[1024];                 // nbkt <= 1024
  int e0 = blockIdx.x * EPB;
  int rem = min(EPB, E - e0);             // edges in this block
  for (int i = threadIdx.x; i < nbkt; i += 256) h[i] = 0;
  __syncthreads();

  int cv[16];
  const int t4 = threadIdx.x << 2;        // 4 consecutive edges per load
#pragma unroll
  for (int k = 0; k < 4; ++k) {
    int base = t4 + (k << 10);            // + k*1024
    if (base + 3 < rem) {
      int4 c4 = *reinterpret_cast<const int4*>(col + e0 + base);
      cv[4 * k + 0] = c4.x; cv[4 * k + 1] = c4.y;
      cv[4 * k + 2] = c4.z; cv[4 * k + 3] = c4.w;
      atomicAdd(&h[c4.x >> BKT_SHIFT], 1);
      atomicAdd(&h[c4.y >> BKT_SHIFT], 1);
      atomicAdd(&h[c4.z >> BKT_SHIFT], 1);
      atomicAdd(&h[c4.w >> BKT_SHIFT], 1);
    } else {
#pragma unroll
      for (int j = 0; j < 4; ++j) {
        int li = base + j;
        int c = (li < rem) ? col[e0 + li] : -1;
        cv[4 * k + j] = c;
        if (c >= 0) atomicAdd(&h[c >> BKT_SHIFT], 1);
      }
    }
  }
  __syncthreads();
  for (int i = threadIdx.x; i < nbkt; i += 256) {
    int c = h[i];
    h[i] = c ? atomicAdd(&bcursor[i], c) : 0;   // reserve range, h -> base
  }
  __syncthreads();
#pragma unroll
  for (int k = 0; k < 4; ++k) {
    int base = t4 + (k << 10);
    if (base + 3 < rem) {
      int4 r4 = *reinterpret_cast<const int4*>(row + e0 + base);
      int c0 = cv[4 * k + 0], c1 = cv[4 * k + 1];
      int c2 = cv[4 * k + 2], c3 = cv[4 * k + 3];
      int p0 = atomicAdd(&h[c0 >> BKT_SHIFT], 1);
      int p1 = atomicAdd(&h[c1 >> BKT_SHIFT], 1);
      int p2 = atomicAdd(&h[c2 >> BKT_SHIFT], 1);
      int p3 = atomicAdd(&h[c3 >> BKT_SHIFT], 1);
      tmp[p0] = r4.x | ((c0 & (BKT_NODES - 1)) << 20);
      tmp[p1] = r4.y | ((c1 & (BKT_NODES - 1)) << 20);
      tmp[p2] = r4.z | ((c2 & (BKT_NODES - 1)) << 20);
      tmp[p3] = r4.w | ((c3 & (BKT_NODES - 1)) << 20);
    } else {
#pragma unroll
      for (int j = 0; j < 4; ++j) {
        int li = base + j;
        int c = cv[4 * k + j];
        if (c >= 0) {
          int r = row[e0 + li];
          int p = atomicAdd(&h[c >> BKT_SHIFT], 1);
          tmp[p] = r | ((c & (BKT_NODES - 1)) << 20);
        }
      }
    }
  }
}

// per-bucket counting sort -> pad8 per-node CSR; deg stats; z0 (slice layout)
__global__ __launch_bounds__(256)
void k_sort(const int* __restrict__ bcursor, const int* __restrict__ tmp,
            int* __restrict__ srcs, int* __restrict__ obeg, int* __restrict__ oend,
            float* __restrict__ invdeg, float* __restrict__ sdeg,
            const float* __restrict__ emb, unsigned* __restrict__ z0,
            int n, int sstu) {
  __shared__ int hist[BKT_NODES];
  __shared__ int excl[BKT_NODES];
  __shared__ int cur[BKT_NODES];
  __shared__ float sdis[BKT_NODES];
  int b = blockIdx.x;
  int base = b * BKT_CAP;
  int cnt = bcursor[b] - base;
  if (threadIdx.x < BKT_NODES) hist[threadIdx.x] = 0;
  __syncthreads();
  for (int q = threadIdx.x; q < cnt; q += 256)
    atomicAdd(&hist[(unsigned)tmp[base + q] >> 20], 1);
  __syncthreads();
  if (threadIdx.x < 64) {     // scan PAD8 lengths; lane l owns bins 2l, 2l+1
    int l = threadIdx.x;
    int h0 = hist[2 * l], h1 = hist[2 * l + 1];
    int p0 = (h0 + 7) & ~7, p1 = (h1 + 7) & ~7;
    int v = p0 + p1;
    int incl = wave_scan_incl(v, l);
    int ex = incl - v;
    excl[2 * l] = ex;      excl[2 * l + 1] = ex + p0;
    cur[2 * l] = ex;       cur[2 * l + 1] = ex + p0;
  }
  __syncthreads();
  int node0 = b << BKT_SHIFT;
  if (threadIdx.x < BKT_NODES) {
    int node = node0 + threadIdx.x;
    if (node < n) {
      int d = hist[threadIdx.x];
      int dpad = (d + 7) & ~7;
      int bg = base + excl[threadIdx.x];
      obeg[node] = bg;
      oend[node] = bg + dpad;                 // padded end for the walk
      float fd = (float)d;
      invdeg[node] = d ? 1.0f / fd : 0.0f;
      sdeg[node] = sqrtf(fd);
      sdis[threadIdx.x] = d ? rsqrtf(fd) : 0.0f;
      for (int p = d; p < dpad; ++p) srcs[bg + p] = n;   // dummy -> zero row
    } else {
      sdis[threadIdx.x] = 0.0f;
    }
  }
  __syncthreads();
  for (int q = threadIdx.x; q < cnt; q += 256) {
    int rec = tmp[base + q];
    int lc = (unsigned)rec >> 20;
    int p = atomicAdd(&cur[lc], 1);
    srcs[base + p] = rec & 0xFFFFF;
  }
  // z0 = bf16(dis * emb) in slice layout: dims 8q..8q+7 -> slice q>>1,
  // uint offset (q&1)*4 within the node's 8-uint slice row.
  int nloc = min(BKT_NODES, n - node0);
  for (int t = threadIdx.x; t < nloc * 8; t += 256) {
    int rr = t >> 3, q = t & 7;
    int node = node0 + rr;
    float ds = sdis[rr];
    float4 v0 = reinterpret_cast<const float4*>(emb)[(size_t)node * 16 + 2 * q];
    float4 v1 = reinterpret_cast<const float4*>(emb)[(size_t)node * 16 + 2 * q + 1];
    uint4 o;
    o.x = cvt_pk_bf16(v0.x * ds, v0.y * ds);
    o.y = cvt_pk_bf16(v0.z * ds, v0.w * ds);
    o.z = cvt_pk_bf16(v1.x * ds, v1.y * ds);
    o.w = cvt_pk_bf16(v1.z * ds, v1.w * ds);
    unsigned* dst = z0 + (size_t)(q >> 1) * sstu + (size_t)node * 8 + (q & 1) * 4;
    *reinterpret_cast<uint4*>(dst) = o;
  }
}

// DIM-SLICED prop: slice = blockIdx&3 (16 dims); 4 lanes/node (lane = 4 dims
// = uint2), 16 nodes/wave, 64 nodes/block; 8-edge (2-quad) guard-free unroll.
template <bool FINAL>
__global__ __launch_bounds__(256)
void k_prop(const int* __restrict__ obeg, const int* __restrict__ oend,
            const int* __restrict__ srcs, const unsigned* __restrict__ z,
            unsigned* __restrict__ zout, const float* __restrict__ invdeg,
            const float* __restrict__ emb, const unsigned* __restrict__ z1,
            const unsigned* __restrict__ z2, const float* __restrict__ sdeg,
            float* __restrict__ out, int n, int sstu) {
  int slice = blockIdx.x & 3;
  int nb = blockIdx.x >> 2;
  int wave = threadIdx.x >> 6;
  int lane = threadIdx.x & 63;
  int grp = lane >> 2, l = lane & 2 ? (lane & 3) : (lane & 3);  // l = lane&3
  l = lane & 3;
  int node = (nb * 4 + wave) * 16 + grp;
  if (node >= n) return;

  const uint2* zs = reinterpret_cast<const uint2*>(z + (size_t)slice * sstu);
  const int4* sv = reinterpret_cast<const int4*>(srcs);
  const unsigned c_lo = 0x00003F80u;   // B=(1.0bf16, 0)  -> adds lo half
  const unsigned c_hi = 0x3F800000u;   // B=(0, 1.0bf16)  -> adds hi half

  int kq = obeg[node] >> 2;       // even (pad8)
  int endq = oend[node] >> 2;

  float s0 = 0.f, s1 = 0.f, s2 = 0.f, s3 = 0.f;

  int4 sqA = make_int4(0, 0, 0, 0), sqB = sqA;
  if (kq < endq) { sqA = sv[kq]; sqB = sv[kq + 1]; }
  while (kq < endq) {
    uint2 a0 = zs[(size_t)sqA.x * 4 + l];
    uint2 a1 = zs[(size_t)sqA.y * 4 + l];
    uint2 a2 = zs[(size_t)sqA.z * 4 + l];
    uint2 a3 = zs[(size_t)sqA.w * 4 + l];
    uint2 b0 = zs[(size_t)sqB.x * 4 + l];
    uint2 b1 = zs[(size_t)sqB.y * 4 + l];
    uint2 b2 = zs[(size_t)sqB.z * 4 + l];
    uint2 b3 = zs[(size_t)sqB.w * 4 + l];
    kq += 2;
    int nk = (kq < endq) ? kq : (kq - 2);   // harmless re-read at the tail
    sqA = sv[nk];
    sqB = sv[nk + 1];
    ACC2(a0.x, s0, s1); ACC2(a0.y, s2, s3);
    ACC2(a1.x, s0, s1); ACC2(a1.y, s2, s3);
    ACC2(a2.x, s0, s1); ACC2(a2.y, s2, s3);
    ACC2(a3.x, s0, s1); ACC2(a3.y, s2, s3);
    ACC2(b0.x, s0, s1); ACC2(b0.y, s2, s3);
    ACC2(b1.x, s0, s1); ACC2(b1.y, s2, s3);
    ACC2(b2.x, s0, s1); ACC2(b2.y, s2, s3);
    ACC2(b3.x, s0, s1); ACC2(b3.y, s2, s3);
  }

  float idg = invdeg[node];
  size_t gi = (size_t)node * 4 + l;        // uint2 index within slice
  if (!FINAL) {
    uint2 o;
    o.x = cvt_pk_bf16(s0 * idg, s1 * idg);
    o.y = cvt_pk_bf16(s2 * idg, s3 * idg);
    reinterpret_cast<uint2*>(zout + (size_t)slice * sstu)[gi] = o;
  } else {
    float sd = sdeg[node];
    float cc = sd * idg;
    uint2 a1 = reinterpret_cast<const uint2*>(z1 + (size_t)slice * sstu)[gi];
    uint2 a2 = reinterpret_cast<const uint2*>(z2 + (size_t)slice * sstu)[gi];
    float4 e = reinterpret_cast<const float4*>(emb)[(size_t)node * 16 + slice * 4 + l];
    float4 o;
    o.x = 0.25f * (e.x + sd * (lo2f(a1.x) + lo2f(a2.x)) + cc * s0);
    o.y = 0.25f * (e.y + sd * (hi2f(a1.x) + hi2f(a2.x)) + cc * s1);
    o.z = 0.25f * (e.z + sd * (lo2f(a1.y) + lo2f(a2.y)) + cc * s2);
    o.w = 0.25f * (e.w + sd * (hi2f(a1.y) + hi2f(a2.y)) + cc * s3);
    reinterpret_cast<float4*>(out)[(size_t)node * 16 + slice * 4 + l] = o;
  }
}

extern "C" void kernel_launch(void* const* d_in, const int* in_sizes, int n_in,
                              void* d_out, int out_size, void* d_ws, size_t ws_size,
                              hipStream_t stream) {
  const int* edge = (const int*)d_in[0];
  const float* emb = (const float*)d_in[1];
  float* out = (float*)d_out;

  const int E = in_sizes[0] / 2;
  const int n = in_sizes[1] / 64;
  const int* row = edge;        // sources j
  const int* col = edge + E;    // targets i
  const int NBKT = (n + BKT_NODES - 1) / BKT_NODES;   // 782
  const int SSTU = (n + 1) * 8;                        // slice stride in uints

  char* ws = (char*)d_ws;
  size_t off = 0;
  auto alloc = [&](size_t bytes) -> void* {
    void* p = ws + off;
    off += (bytes + 255) & ~(size_t)255;
    return p;
  };
  int*   bcursor = (int*)  alloc((size_t)NBKT * 4);
  int*   tmp     = (int*)  alloc((size_t)NBKT * BKT_CAP * 4);   // ~8.8 MB
  int*   srcs    = (int*)  alloc((size_t)NBKT * BKT_CAP * 4);   // ~8.8 MB
  int*   obeg    = (int*)  alloc((size_t)n * 4);
  int*   oend    = (int*)  alloc((size_t)n * 4);
  float* invdeg  = (float*)alloc((size_t)n * 4);
  float* sdeg    = (float*)alloc((size_t)n * 4);
  unsigned* z0   = (unsigned*)alloc((size_t)4 * SSTU * 4);      // 12.8 MB
  unsigned* z1   = (unsigned*)alloc((size_t)4 * SSTU * 4);
  unsigned* z2   = (unsigned*)alloc((size_t)4 * SSTU * 4);
  (void)ws_size; (void)n_in; (void)out_size;

  const int NBB = (E + EPB - 1) / EPB;    // 306
  k_init<<<(NBKT + 255) / 256, 256, 0, stream>>>(bcursor, NBKT, z0, z1, z2, n, SSTU);
  k_bin<<<NBB, 256, 0, stream>>>(row, col, bcursor, tmp, E, NBKT);
  k_sort<<<NBKT, 256, 0, stream>>>(bcursor, tmp, srcs, obeg, oend,
                                   invdeg, sdeg, emb, z0, n, SSTU);

  // dim-sliced props: 64 nodes/block, 4 slice-variants interleaved in bid
  const int NBS = (n + 63) / 64;          // node-blocks per slice
  const int pg = NBS * 4;
  k_prop<false><<<pg, 256, 0, stream>>>(obeg, oend, srcs, z0, z1, invdeg,
                                        nullptr, nullptr, nullptr, nullptr, nullptr, n, SSTU);
  k_prop<false><<<pg, 256, 0, stream>>>(obeg, oend, srcs, z1, z2, invdeg,
                                        nullptr, nullptr, nullptr, nullptr, nullptr, n, SSTU);
  k_prop<true ><<<pg, 256, 0, stream>>>(obeg, oend, srcs, z2, nullptr, invdeg,
                                        emb, z1, z2, sdeg, out, n, SSTU);
}

// Round 17
// 120.420 us; speedup vs baseline: 1.3644x; 1.3644x over previous
//
#include <hip/hip_runtime.h>

// LightGCN, z-form: z = dis(.)x  =>  z_k[c] = invdeg_c * sum_{r->c} z_{k-1}[r]
//   out = 0.25*(emb + sdeg (.) (z1+z2+z3)),  sdeg = sqrt(deg), dis = 1/sdeg.
// Build: radix partition by target bucket (128 nodes), per-bucket counting
// sort -> per-node CSR PADDED to multiple of 8 (dummy src = n -> zero row).
// Prop: 8-lane group per node (8 nodes/wave), lane = uint4 = 8 bf16 dims,
// guard-free 8-edge (2-quad) unroll; bf16 accumulate via v_dot2_f32_bf16.
// FINAL STATE (R17 = revert to best R14 config, 120.6us):
//  - props are L2-fill-fabric-bound: FETCH == 8 XCD x 12.8MB z compulsory
//    fill at ~4 TB/s aggregate; MLP depth (R9/R10), VALU count (R12),
//    source sorting (R11/R15), dim slicing (R16) all null or regressions.
//  - coop fusion (R8/R9) 6x slower on this platform; abandoned.
//  - fp8 z fails the 2.79e-3 absmax budget; bf16 z gives 4.9e-4.

#define BKT_SHIFT 7
#define BKT_NODES 128
#define BKT_CAP   2816      // mean 1600 edges + pad8 + slack
#define EPB       4096      // edges per k_bin block (306 blocks, 16/thread)

__device__ __forceinline__ float lo2f(unsigned u) { return __uint_as_float(u << 16); }
__device__ __forceinline__ float hi2f(unsigned u) { return __uint_as_float(u & 0xFFFF0000u); }
__device__ __forceinline__ unsigned cvt_pk_bf16(float lo, float hi) {
  unsigned r;
  asm("v_cvt_pk_bf16_f32 %0, %1, %2" : "=v"(r) : "v"(lo), "v"(hi));
  return r;
}

// s_lo += bf16_lo(u); s_hi += bf16_hi(u)  — one v_dot2 each (B=(1,0)/(0,1))
#define ACC2(u, slo, shi)                                                     \
  asm("v_dot2_f32_bf16 %0, %1, %2, %0" : "+v"(slo) : "v"(u), "v"(c_lo));      \
  asm("v_dot2_f32_bf16 %0, %1, %2, %0" : "+v"(shi) : "v"(u), "v"(c_hi));

__device__ __forceinline__ int wave_scan_incl(int v, int lane) {
#pragma unroll
  for (int off = 1; off < 64; off <<= 1) {
    int t = __shfl_up(v, off, 64);
    if (lane >= off) v += t;
  }
  return v;
}

// init bucket cursors + zero the dummy row n of z0/z1/z2
__global__ void k_init(int* __restrict__ bcursor, int nbkt,
                       unsigned* __restrict__ z0, unsigned* __restrict__ z1,
                       unsigned* __restrict__ z2, int n) {
  int i = blockIdx.x * blockDim.x + threadIdx.x;
  if (i < nbkt) bcursor[i] = i * BKT_CAP;
  if (blockIdx.x == 0 && threadIdx.x < 32) {     // row = 64 bf16 = 32 uints
    size_t o = (size_t)n * 32 + threadIdx.x;
    z0[o] = 0u; z1[o] = 0u; z2[o] = 0u;
  }
}

// radix partition by target bucket; col read ONCE into registers (int4),
// 4-wide unrolled LDS-atomic phases, grouped reservation (1 global atomic
// per (block,bin)).
__global__ __launch_bounds__(256)
void k_bin(const int* __restrict__ row, const int* __restrict__ col,
           int* __restrict__ bcursor, int* __restrict__ tmp, int E, int nbkt) {
  __shared__ int h[1024];                 // nbkt <= 1024
  int e0 = blockIdx.x * EPB;
  int rem = min(EPB, E - e0);             // edges in this block
  for (int i = threadIdx.x; i < nbkt; i += 256) h[i] = 0;
  __syncthreads();

  int cv[16];
  const int t4 = threadIdx.x << 2;        // 4 consecutive edges per load
#pragma unroll
  for (int k = 0; k < 4; ++k) {
    int base = t4 + (k << 10);            // + k*1024
    if (base + 3 < rem) {
      int4 c4 = *reinterpret_cast<const int4*>(col + e0 + base);
      cv[4 * k + 0] = c4.x; cv[4 * k + 1] = c4.y;
      cv[4 * k + 2] = c4.z; cv[4 * k + 3] = c4.w;
      atomicAdd(&h[c4.x >> BKT_SHIFT], 1);
      atomicAdd(&h[c4.y >> BKT_SHIFT], 1);
      atomicAdd(&h[c4.z >> BKT_SHIFT], 1);
      atomicAdd(&h[c4.w >> BKT_SHIFT], 1);
    } else {
#pragma unroll
      for (int j = 0; j < 4; ++j) {
        int li = base + j;
        int c = (li < rem) ? col[e0 + li] : -1;
        cv[4 * k + j] = c;
        if (c >= 0) atomicAdd(&h[c >> BKT_SHIFT], 1);
      }
    }
  }
  __syncthreads();
  for (int i = threadIdx.x; i < nbkt; i += 256) {
    int c = h[i];
    h[i] = c ? atomicAdd(&bcursor[i], c) : 0;   // reserve range, h -> base
  }
  __syncthreads();
#pragma unroll
  for (int k = 0; k < 4; ++k) {
    int base = t4 + (k << 10);
    if (base + 3 < rem) {
      int4 r4 = *reinterpret_cast<const int4*>(row + e0 + base);
      int c0 = cv[4 * k + 0], c1 = cv[4 * k + 1];
      int c2 = cv[4 * k + 2], c3 = cv[4 * k + 3];
      int p0 = atomicAdd(&h[c0 >> BKT_SHIFT], 1);
      int p1 = atomicAdd(&h[c1 >> BKT_SHIFT], 1);
      int p2 = atomicAdd(&h[c2 >> BKT_SHIFT], 1);
      int p3 = atomicAdd(&h[c3 >> BKT_SHIFT], 1);
      tmp[p0] = r4.x | ((c0 & (BKT_NODES - 1)) << 20);
      tmp[p1] = r4.y | ((c1 & (BKT_NODES - 1)) << 20);
      tmp[p2] = r4.z | ((c2 & (BKT_NODES - 1)) << 20);
      tmp[p3] = r4.w | ((c3 & (BKT_NODES - 1)) << 20);
    } else {
#pragma unroll
      for (int j = 0; j < 4; ++j) {
        int li = base + j;
        int c = cv[4 * k + j];
        if (c >= 0) {
          int r = row[e0 + li];
          int p = atomicAdd(&h[c >> BKT_SHIFT], 1);
          tmp[p] = r | ((c & (BKT_NODES - 1)) << 20);
        }
      }
    }
  }
}

// per-bucket counting sort -> pad8 per-node CSR; deg stats; z0 = bf16(dis*emb)
__global__ __launch_bounds__(256)
void k_sort(const int* __restrict__ bcursor, const int* __restrict__ tmp,
            int* __restrict__ srcs, int* __restrict__ obeg, int* __restrict__ oend,
            float* __restrict__ invdeg, float* __restrict__ sdeg,
            const float* __restrict__ emb, unsigned short* __restrict__ z0, int n) {
  __shared__ int hist[BKT_NODES];
  __shared__ int excl[BKT_NODES];
  __shared__ int cur[BKT_NODES];
  __shared__ float sdis[BKT_NODES];
  int b = blockIdx.x;
  int base = b * BKT_CAP;
  int cnt = bcursor[b] - base;
  if (threadIdx.x < BKT_NODES) hist[threadIdx.x] = 0;
  __syncthreads();
  for (int q = threadIdx.x; q < cnt; q += 256)
    atomicAdd(&hist[(unsigned)tmp[base + q] >> 20], 1);
  __syncthreads();
  if (threadIdx.x < 64) {     // scan PAD8 lengths; lane l owns bins 2l, 2l+1
    int l = threadIdx.x;
    int h0 = hist[2 * l], h1 = hist[2 * l + 1];
    int p0 = (h0 + 7) & ~7, p1 = (h1 + 7) & ~7;
    int v = p0 + p1;
    int incl = wave_scan_incl(v, l);
    int ex = incl - v;
    excl[2 * l] = ex;      excl[2 * l + 1] = ex + p0;
    cur[2 * l] = ex;       cur[2 * l + 1] = ex + p0;
  }
  __syncthreads();
  int node0 = b << BKT_SHIFT;
  if (threadIdx.x < BKT_NODES) {
    int node = node0 + threadIdx.x;
    if (node < n) {
      int d = hist[threadIdx.x];
      int dpad = (d + 7) & ~7;
      int bg = base + excl[threadIdx.x];
      obeg[node] = bg;
      oend[node] = bg + dpad;                 // padded end for the walk
      float fd = (float)d;
      invdeg[node] = d ? 1.0f / fd : 0.0f;
      sdeg[node] = sqrtf(fd);
      sdis[threadIdx.x] = d ? rsqrtf(fd) : 0.0f;
      for (int p = d; p < dpad; ++p) srcs[bg + p] = n;   // dummy -> zero row
    } else {
      sdis[threadIdx.x] = 0.0f;
    }
  }
  __syncthreads();
  for (int q = threadIdx.x; q < cnt; q += 256) {
    int rec = tmp[base + q];
    int lc = (unsigned)rec >> 20;
    int p = atomicAdd(&cur[lc], 1);
    srcs[base + p] = rec & 0xFFFFF;
  }
  int nloc = min(BKT_NODES, n - node0);
  for (int t = threadIdx.x; t < nloc * 8; t += 256) {
    int rr = t >> 3, q = t & 7;
    float ds = sdis[rr];
    float4 v0 = reinterpret_cast<const float4*>(emb)[(size_t)(node0 + rr) * 16 + 2 * q];
    float4 v1 = reinterpret_cast<const float4*>(emb)[(size_t)(node0 + rr) * 16 + 2 * q + 1];
    uint4 o;
    o.x = cvt_pk_bf16(v0.x * ds, v0.y * ds);
    o.y = cvt_pk_bf16(v0.z * ds, v0.w * ds);
    o.z = cvt_pk_bf16(v1.x * ds, v1.y * ds);
    o.w = cvt_pk_bf16(v1.z * ds, v1.w * ds);
    reinterpret_cast<uint4*>(z0)[(size_t)(node0 + rr) * 8 + q] = o;
  }
}

// 8-lane group per node, 8 nodes per wave; lane l covers dims 8l..8l+7 (uint4).
// Guard-free 2-quad (8-edge) unroll over pad8 CSR; dot2-based accumulate.
template <bool FINAL>
__global__ __launch_bounds__(256)
void k_prop(const int* __restrict__ obeg, const int* __restrict__ oend,
            const int* __restrict__ srcs, const unsigned short* __restrict__ z,
            unsigned short* __restrict__ zout, const float* __restrict__ invdeg,
            const float* __restrict__ emb, const unsigned short* __restrict__ z1,
            const unsigned short* __restrict__ z2, const float* __restrict__ sdeg,
            float* __restrict__ out, int n) {
  int lane = threadIdx.x & 63;
  int wid = (blockIdx.x * blockDim.x + threadIdx.x) >> 6;   // global wave id
  int g = lane >> 3, l = lane & 7;
  int node = wid * 8 + g;
  if (node >= n) return;
  const uint4* zv = reinterpret_cast<const uint4*>(z);      // row = 8 x uint4
  const int4* sv = reinterpret_cast<const int4*>(srcs);

  const unsigned c_lo = 0x00003F80u;   // B=(1.0bf16, 0)  -> adds lo half
  const unsigned c_hi = 0x3F800000u;   // B=(0, 1.0bf16)  -> adds hi half

  int kq = obeg[node] >> 2;       // even by construction (pad8)
  int endq = oend[node] >> 2;     // endq - kq is even

  float s0 = 0.f, s1 = 0.f, s2 = 0.f, s3 = 0.f;
  float s4 = 0.f, s5 = 0.f, s6 = 0.f, s7 = 0.f;

  int4 sqA = make_int4(0, 0, 0, 0), sqB = sqA;
  if (kq < endq) { sqA = sv[kq]; sqB = sv[kq + 1]; }
  while (kq < endq) {
    uint4 a0 = zv[(size_t)sqA.x * 8 + l];
    uint4 a1 = zv[(size_t)sqA.y * 8 + l];
    uint4 a2 = zv[(size_t)sqA.z * 8 + l];
    uint4 a3 = zv[(size_t)sqA.w * 8 + l];
    uint4 b0 = zv[(size_t)sqB.x * 8 + l];
    uint4 b1 = zv[(size_t)sqB.y * 8 + l];
    uint4 b2 = zv[(size_t)sqB.z * 8 + l];
    uint4 b3 = zv[(size_t)sqB.w * 8 + l];
    kq += 2;
    int nk = (kq < endq) ? kq : (kq - 2);   // harmless re-read at the tail
    sqA = sv[nk];
    sqB = sv[nk + 1];
    ACC2(a0.x, s0, s1); ACC2(a0.y, s2, s3); ACC2(a0.z, s4, s5); ACC2(a0.w, s6, s7);
    ACC2(a1.x, s0, s1); ACC2(a1.y, s2, s3); ACC2(a1.z, s4, s5); ACC2(a1.w, s6, s7);
    ACC2(a2.x, s0, s1); ACC2(a2.y, s2, s3); ACC2(a2.z, s4, s5); ACC2(a2.w, s6, s7);
    ACC2(a3.x, s0, s1); ACC2(a3.y, s2, s3); ACC2(a3.z, s4, s5); ACC2(a3.w, s6, s7);
    ACC2(b0.x, s0, s1); ACC2(b0.y, s2, s3); ACC2(b0.z, s4, s5); ACC2(b0.w, s6, s7);
    ACC2(b1.x, s0, s1); ACC2(b1.y, s2, s3); ACC2(b1.z, s4, s5); ACC2(b1.w, s6, s7);
    ACC2(b2.x, s0, s1); ACC2(b2.y, s2, s3); ACC2(b2.z, s4, s5); ACC2(b2.w, s6, s7);
    ACC2(b3.x, s0, s1); ACC2(b3.y, s2, s3); ACC2(b3.z, s4, s5); ACC2(b3.w, s6, s7);
  }

  float idg = invdeg[node];
  size_t gi = (size_t)node * 8 + l;
  if (!FINAL) {
    uint4 o;
    o.x = cvt_pk_bf16(s0 * idg, s1 * idg);
    o.y = cvt_pk_bf16(s2 * idg, s3 * idg);
    o.z = cvt_pk_bf16(s4 * idg, s5 * idg);
    o.w = cvt_pk_bf16(s6 * idg, s7 * idg);
    reinterpret_cast<uint4*>(zout)[gi] = o;
  } else {
    float sd = sdeg[node];
    float c = sd * idg;
    uint4 a1 = reinterpret_cast<const uint4*>(z1)[gi];
    uint4 a2 = reinterpret_cast<const uint4*>(z2)[gi];
    float4 e0 = reinterpret_cast<const float4*>(emb)[(size_t)node * 16 + 2 * l];
    float4 e1 = reinterpret_cast<const float4*>(emb)[(size_t)node * 16 + 2 * l + 1];
    float4 o0, o1;
    o0.x = 0.25f * (e0.x + sd * (lo2f(a1.x) + lo2f(a2.x)) + c * s0);
    o0.y = 0.25f * (e0.y + sd * (hi2f(a1.x) + hi2f(a2.x)) + c * s1);
    o0.z = 0.25f * (e0.z + sd * (lo2f(a1.y) + lo2f(a2.y)) + c * s2);
    o0.w = 0.25f * (e0.w + sd * (hi2f(a1.y) + hi2f(a2.y)) + c * s3);
    o1.x = 0.25f * (e1.x + sd * (lo2f(a1.z) + lo2f(a2.z)) + c * s4);
    o1.y = 0.25f * (e1.y + sd * (hi2f(a1.z) + hi2f(a2.z)) + c * s5);
    o1.z = 0.25f * (e1.z + sd * (lo2f(a1.w) + lo2f(a2.w)) + c * s6);
    o1.w = 0.25f * (e1.w + sd * (hi2f(a1.w) + hi2f(a2.w)) + c * s7);
    reinterpret_cast<float4*>(out)[(size_t)node * 16 + 2 * l] = o0;
    reinterpret_cast<float4*>(out)[(size_t)node * 16 + 2 * l + 1] = o1;
  }
}

extern "C" void kernel_launch(void* const* d_in, const int* in_sizes, int n_in,
                              void* d_out, int out_size, void* d_ws, size_t ws_size,
                              hipStream_t stream) {
  const int* edge = (const int*)d_in[0];
  const float* emb = (const float*)d_in[1];
  float* out = (float*)d_out;

  const int E = in_sizes[0] / 2;
  const int n = in_sizes[1] / 64;
  const int* row = edge;        // sources j
  const int* col = edge + E;    // targets i
  const int NBKT = (n + BKT_NODES - 1) / BKT_NODES;   // 782

  char* ws = (char*)d_ws;
  size_t off = 0;
  auto alloc = [&](size_t bytes) -> void* {
    void* p = ws + off;
    off += (bytes + 255) & ~(size_t)255;
    return p;
  };
  int*   bcursor = (int*)  alloc((size_t)NBKT * 4);
  int*   tmp     = (int*)  alloc((size_t)NBKT * BKT_CAP * 4);   // ~8.8 MB
  int*   srcs    = (int*)  alloc((size_t)NBKT * BKT_CAP * 4);   // ~8.8 MB
  int*   obeg    = (int*)  alloc((size_t)n * 4);
  int*   oend    = (int*)  alloc((size_t)n * 4);
  float* invdeg  = (float*)alloc((size_t)n * 4);
  float* sdeg    = (float*)alloc((size_t)n * 4);
  unsigned short* z0 = (unsigned short*)alloc((size_t)(n + 1) * 64 * 2);
  unsigned short* z1 = (unsigned short*)alloc((size_t)(n + 1) * 64 * 2);
  unsigned short* z2 = (unsigned short*)alloc((size_t)(n + 1) * 64 * 2);
  (void)ws_size; (void)n_in; (void)out_size;

  const int NBB = (E + EPB - 1) / EPB;    // 306
  k_init<<<(NBKT + 255) / 256, 256, 0, stream>>>(bcursor, NBKT,
      (unsigned*)z0, (unsigned*)z1, (unsigned*)z2, n);
  k_bin<<<NBB, 256, 0, stream>>>(row, col, bcursor, tmp, E, NBKT);
  k_sort<<<NBKT, 256, 0, stream>>>(bcursor, tmp, srcs, obeg, oend,
                                   invdeg, sdeg, emb, z0, n);

  // 8 nodes per wave, 4 waves per block = 32 nodes/block
  const int pg = (n + 31) / 32;
  k_prop<false><<<pg, 256, 0, stream>>>(obeg, oend, srcs, z0, z1, invdeg,
                                        nullptr, nullptr, nullptr, nullptr, nullptr, n);
  k_prop<false><<<pg, 256, 0, stream>>>(obeg, oend, srcs, z1, z2, invdeg,
                                        nullptr, nullptr, nullptr, nullptr, nullptr, n);
  k_prop<true ><<<pg, 256, 0, stream>>>(obeg, oend, srcs, z2, nullptr, invdeg,
                                        emb, z1, z2, sdeg, out, n);
}